// Round 1
// baseline (913.855 us; speedup 1.0000x reference)
//
#include <hip/hip_runtime.h>
#include <hip/hip_bf16.h>
#include <stdint.h>

// Problem: B=8192, N=32, D_IN=D_HID=D_OUT=512
#define D 512

typedef __attribute__((ext_vector_type(8))) short short8_t;
typedef __attribute__((ext_vector_type(4))) float floatx4;

static __device__ __forceinline__ unsigned short f2bf(float f) {
    union { __hip_bfloat16 h; unsigned short u; } c;
    c.h = __float2bfloat16(f);
    return c.u;
}

// ---------------------------------------------------------------------------
// Kernel C: transpose + convert the three 512x512 f32 weights to bf16 [n][k]
// ---------------------------------------------------------------------------
__global__ void __launch_bounds__(256) prep_weights(
    const float* __restrict__ w1, const float* __restrict__ w2,
    const float* __restrict__ w3,
    unsigned short* __restrict__ w1t, unsigned short* __restrict__ w2t,
    unsigned short* __restrict__ w3t)
{
    int idx = blockIdx.x * 256 + threadIdx.x;   // 0 .. 3*512*512
    int m = idx >> 18;                          // which matrix
    int i = idx & 262143;                       // k*512 + n (coalesced read)
    int k = i >> 9, n = i & 511;
    const float* src = (m == 0) ? w1 : (m == 1) ? w2 : w3;
    unsigned short* dst = (m == 0) ? w1t : (m == 1) ? w2t : w3t;
    dst[n * D + k] = f2bf(src[i]);
}

// ---------------------------------------------------------------------------
// Kernel A: h = neigh[262144,512] @ W1 ; pooled[b,:] = relu(max_n h + bias)
// 128x128 C-tile per block, 4 waves of 64x64, BK=64, 16x16x32 bf16 MFMA.
// A 128-row M-tile == 4 aligned batch-groups of 32 neighbors -> pool in-block.
// LDS chunk xor-swizzle: chunk for global k-chunk g of row r stored at g^(r&7).
// ---------------------------------------------------------------------------
__global__ void __launch_bounds__(256) mlp_pool_kernel(
    const float* __restrict__ neigh,          // [B*32, 512] f32
    const unsigned short* __restrict__ w1t,   // [512,512] bf16, [n][k]
    const float* __restrict__ bias,           // [512] f32
    unsigned short* __restrict__ pooled)      // [B, 512] bf16
{
    __shared__ __align__(16) short As[128 * 64];
    __shared__ __align__(16) short Bs[128 * 64];
    __shared__ float pool_s[4][128];

    const int tid  = threadIdx.x;
    const int wave = tid >> 6;
    const int lane = tid & 63;
    const int quad = lane >> 4;
    const int l15  = lane & 15;
    const int mw = (wave >> 1) * 64;
    const int nw = (wave & 1) * 64;

    const int m0 = (blockIdx.x >> 2) * 128;   // row tile in [B*32]
    const int n0 = (blockIdx.x & 3) * 128;    // col tile in D_HID

    floatx4 acc[4][4];
#pragma unroll
    for (int i = 0; i < 4; ++i)
#pragma unroll
        for (int j = 0; j < 4; ++j) acc[i][j] = (floatx4){0.f, 0.f, 0.f, 0.f};

    for (int kk = 0; kk < 8; ++kk) {
        const int k0 = kk * 64;
        __syncthreads();
        // ---- stage A: 128x64 f32 -> bf16, swizzled ----
#pragma unroll
        for (int rnd = 0; rnd < 4; ++rnd) {
            int l = rnd * 256 + tid;
            int r = l >> 3, g = l & 7;
            const float4* src = reinterpret_cast<const float4*>(
                neigh + (size_t)(m0 + r) * D + k0 + g * 8);
            float4 f0 = src[0];
            float4 f1 = src[1];
            short8_t v;
            v[0] = (short)f2bf(f0.x); v[1] = (short)f2bf(f0.y);
            v[2] = (short)f2bf(f0.z); v[3] = (short)f2bf(f0.w);
            v[4] = (short)f2bf(f1.x); v[5] = (short)f2bf(f1.y);
            v[6] = (short)f2bf(f1.z); v[7] = (short)f2bf(f1.w);
            *reinterpret_cast<short8_t*>(&As[r * 64 + ((g ^ (r & 7)) * 8)]) = v;
        }
        // ---- stage B: 128x64 bf16 direct, swizzled ----
#pragma unroll
        for (int rnd = 0; rnd < 4; ++rnd) {
            int l = rnd * 256 + tid;
            int r = l >> 3, g = l & 7;
            short8_t v = *reinterpret_cast<const short8_t*>(
                w1t + (size_t)(n0 + r) * D + k0 + g * 8);
            *reinterpret_cast<short8_t*>(&Bs[r * 64 + ((g ^ (r & 7)) * 8)]) = v;
        }
        __syncthreads();
        // ---- 2 k-steps of 32, 16 MFMAs each ----
#pragma unroll
        for (int s = 0; s < 2; ++s) {
            short8_t af[4], bfr[4];
#pragma unroll
            for (int mt = 0; mt < 4; ++mt) {
                int r = mw + mt * 16 + l15;
                int c = (s * 4 + quad) ^ (r & 7);
                af[mt] = *reinterpret_cast<const short8_t*>(&As[r * 64 + c * 8]);
            }
#pragma unroll
            for (int nt = 0; nt < 4; ++nt) {
                int r = nw + nt * 16 + l15;
                int c = (s * 4 + quad) ^ (r & 7);
                bfr[nt] = *reinterpret_cast<const short8_t*>(&Bs[r * 64 + c * 8]);
            }
#pragma unroll
            for (int mt = 0; mt < 4; ++mt)
#pragma unroll
                for (int nt = 0; nt < 4; ++nt)
                    acc[mt][nt] = __builtin_amdgcn_mfma_f32_16x16x32_bf16(
                        af[mt], bfr[nt], acc[mt][nt], 0, 0, 0);
        }
    }

    // ---- max-pool over groups of 32 rows (raw h; bias+relu after) ----
    // wave rows = mw..mw+63 = 2 groups; C/D layout: row = quad*4+reg, col = l15
#pragma unroll
    for (int gl = 0; gl < 2; ++gl) {
#pragma unroll
        for (int nt = 0; nt < 4; ++nt) {
            float v = -3.4e38f;
#pragma unroll
            for (int mt = 2 * gl; mt < 2 * gl + 2; ++mt)
#pragma unroll
                for (int rg = 0; rg < 4; ++rg) v = fmaxf(v, acc[mt][nt][rg]);
            v = fmaxf(v, __shfl_xor(v, 16));
            v = fmaxf(v, __shfl_xor(v, 32));
            if (lane < 16) pool_s[(mw >> 5) + gl][nw + nt * 16 + l15] = v;
        }
    }
    __syncthreads();
    for (int i = tid; i < 512; i += 256) {
        int g = i >> 7, col = i & 127;
        float v = fmaxf(pool_s[g][col] + bias[n0 + col], 0.0f);
        pooled[(size_t)((m0 >> 5) + g) * D + n0 + col] = f2bf(v);
    }
}

// ---------------------------------------------------------------------------
// Kernel B: out = relu(pooled @ W2 + self @ W3), M=8192, N=512, K=512 (x2)
// Virtual K-loop of 16 blocks: kk<8 -> pooled/W2t (bf16), kk>=8 -> self/W3t.
// ---------------------------------------------------------------------------
__global__ void __launch_bounds__(256) out_gemm_kernel(
    const unsigned short* __restrict__ pooled, // [B,512] bf16
    const float* __restrict__ selfv,           // [B,512] f32
    const unsigned short* __restrict__ w2t,    // neigh_w^T bf16 [n][k]
    const unsigned short* __restrict__ w3t,    // self_w^T bf16 [n][k]
    float* __restrict__ out)                   // [B,512] f32
{
    __shared__ __align__(16) short As[128 * 64];
    __shared__ __align__(16) short Bs[128 * 64];

    const int tid  = threadIdx.x;
    const int wave = tid >> 6;
    const int lane = tid & 63;
    const int quad = lane >> 4;
    const int l15  = lane & 15;
    const int mw = (wave >> 1) * 64;
    const int nw = (wave & 1) * 64;

    const int m0 = (blockIdx.x >> 2) * 128;
    const int n0 = (blockIdx.x & 3) * 128;

    floatx4 acc[4][4];
#pragma unroll
    for (int i = 0; i < 4; ++i)
#pragma unroll
        for (int j = 0; j < 4; ++j) acc[i][j] = (floatx4){0.f, 0.f, 0.f, 0.f};

    for (int kk = 0; kk < 16; ++kk) {
        const int k0 = (kk & 7) * 64;
        __syncthreads();
        if (kk < 8) {
            // A from pooled (bf16 direct)
#pragma unroll
            for (int rnd = 0; rnd < 4; ++rnd) {
                int l = rnd * 256 + tid;
                int r = l >> 3, g = l & 7;
                short8_t v = *reinterpret_cast<const short8_t*>(
                    pooled + (size_t)(m0 + r) * D + k0 + g * 8);
                *reinterpret_cast<short8_t*>(&As[r * 64 + ((g ^ (r & 7)) * 8)]) = v;
            }
#pragma unroll
            for (int rnd = 0; rnd < 4; ++rnd) {
                int l = rnd * 256 + tid;
                int r = l >> 3, g = l & 7;
                short8_t v = *reinterpret_cast<const short8_t*>(
                    w2t + (size_t)(n0 + r) * D + k0 + g * 8);
                *reinterpret_cast<short8_t*>(&Bs[r * 64 + ((g ^ (r & 7)) * 8)]) = v;
            }
        } else {
            // A from self_vecs (f32 -> bf16)
#pragma unroll
            for (int rnd = 0; rnd < 4; ++rnd) {
                int l = rnd * 256 + tid;
                int r = l >> 3, g = l & 7;
                const float4* src = reinterpret_cast<const float4*>(
                    selfv + (size_t)(m0 + r) * D + k0 + g * 8);
                float4 f0 = src[0];
                float4 f1 = src[1];
                short8_t v;
                v[0] = (short)f2bf(f0.x); v[1] = (short)f2bf(f0.y);
                v[2] = (short)f2bf(f0.z); v[3] = (short)f2bf(f0.w);
                v[4] = (short)f2bf(f1.x); v[5] = (short)f2bf(f1.y);
                v[6] = (short)f2bf(f1.z); v[7] = (short)f2bf(f1.w);
                *reinterpret_cast<short8_t*>(&As[r * 64 + ((g ^ (r & 7)) * 8)]) = v;
            }
#pragma unroll
            for (int rnd = 0; rnd < 4; ++rnd) {
                int l = rnd * 256 + tid;
                int r = l >> 3, g = l & 7;
                short8_t v = *reinterpret_cast<const short8_t*>(
                    w3t + (size_t)(n0 + r) * D + k0 + g * 8);
                *reinterpret_cast<short8_t*>(&Bs[r * 64 + ((g ^ (r & 7)) * 8)]) = v;
            }
        }
        __syncthreads();
#pragma unroll
        for (int s = 0; s < 2; ++s) {
            short8_t af[4], bfr[4];
#pragma unroll
            for (int mt = 0; mt < 4; ++mt) {
                int r = mw + mt * 16 + l15;
                int c = (s * 4 + quad) ^ (r & 7);
                af[mt] = *reinterpret_cast<const short8_t*>(&As[r * 64 + c * 8]);
            }
#pragma unroll
            for (int nt = 0; nt < 4; ++nt) {
                int r = nw + nt * 16 + l15;
                int c = (s * 4 + quad) ^ (r & 7);
                bfr[nt] = *reinterpret_cast<const short8_t*>(&Bs[r * 64 + c * 8]);
            }
#pragma unroll
            for (int mt = 0; mt < 4; ++mt)
#pragma unroll
                for (int nt = 0; nt < 4; ++nt)
                    acc[mt][nt] = __builtin_amdgcn_mfma_f32_16x16x32_bf16(
                        af[mt], bfr[nt], acc[mt][nt], 0, 0, 0);
        }
    }

    // epilogue: relu, scalar f32 stores (C/D layout: row=quad*4+reg, col=l15)
#pragma unroll
    for (int mt = 0; mt < 4; ++mt)
#pragma unroll
        for (int nt = 0; nt < 4; ++nt)
#pragma unroll
            for (int rg = 0; rg < 4; ++rg) {
                int row = m0 + mw + mt * 16 + quad * 4 + rg;
                int col = n0 + nw + nt * 16 + l15;
                out[(size_t)row * D + col] = fmaxf(acc[mt][nt][rg], 0.0f);
            }
}

// ---------------------------------------------------------------------------
extern "C" void kernel_launch(void* const* d_in, const int* in_sizes, int n_in,
                              void* d_out, int out_size, void* d_ws, size_t ws_size,
                              hipStream_t stream) {
    const float* selfv = (const float*)d_in[0];   // [8192,512]
    const float* neigh = (const float*)d_in[1];   // [8192,32,512]
    const float* w1    = (const float*)d_in[2];   // mlp_w [512,512]
    const float* b1    = (const float*)d_in[3];   // mlp_b [512]
    const float* w2    = (const float*)d_in[4];   // neigh_w [512,512]
    const float* w3    = (const float*)d_in[5];   // self_w [512,512]
    float* out = (float*)d_out;

    // ws layout: pooled bf16 [8192*512] (8 MB) | w1t | w2t | w3t (512 KB each)
    unsigned short* pooled = (unsigned short*)d_ws;
    unsigned short* w1t = (unsigned short*)((char*)d_ws + 8388608);
    unsigned short* w2t = w1t + 262144;
    unsigned short* w3t = w2t + 262144;

    prep_weights<<<3072, 256, 0, stream>>>(w1, w2, w3, w1t, w2t, w3t);
    // M-tiles = 262144/128 = 2048, N-tiles = 4
    mlp_pool_kernel<<<8192, 256, 0, stream>>>(neigh, w1t, b1, pooled);
    // M-tiles = 8192/128 = 64, N-tiles = 4
    out_gemm_kernel<<<256, 256, 0, stream>>>(pooled, selfv, w2t, w3t, out);
}

// Round 2
// 836.038 us; speedup vs baseline: 1.0931x; 1.0931x over previous
//
#include <hip/hip_runtime.h>
#include <hip/hip_bf16.h>
#include <stdint.h>

// Problem: B=8192, N=32, D_IN=D_HID=D_OUT=512
#define D 512

typedef __attribute__((ext_vector_type(8))) short short8_t;
typedef __attribute__((ext_vector_type(4))) float floatx4;

static __device__ __forceinline__ unsigned short f2bf(float f) {
    union { __hip_bfloat16 h; unsigned short u; } c;
    c.h = __float2bfloat16(f);
    return c.u;
}

// async global -> LDS, 16 B per lane. LDS dest must be wave-uniform base +
// lane*16 (HW constraint); global vaddr may be per-lane arbitrary.
static __device__ __forceinline__ void ld_lds16(const void* g, void* l) {
    __builtin_amdgcn_global_load_lds(
        (const __attribute__((address_space(1))) void*)g,
        (__attribute__((address_space(3))) void*)l, 16, 0, 0);
}

// ---------------------------------------------------------------------------
// Kernel C: transpose + convert the three 512x512 f32 weights to bf16 [n][k]
// ---------------------------------------------------------------------------
__global__ void __launch_bounds__(256) prep_weights(
    const float* __restrict__ w1, const float* __restrict__ w2,
    const float* __restrict__ w3,
    unsigned short* __restrict__ w1t, unsigned short* __restrict__ w2t,
    unsigned short* __restrict__ w3t)
{
    int idx = blockIdx.x * 256 + threadIdx.x;   // 0 .. 3*512*512
    int m = idx >> 18;                          // which matrix
    int i = idx & 262143;                       // k*512 + n (coalesced read)
    int k = i >> 9, n = i & 511;
    const float* src = (m == 0) ? w1 : (m == 1) ? w2 : w3;
    unsigned short* dst = (m == 0) ? w1t : (m == 1) ? w2t : w3t;
    dst[n * D + k] = f2bf(src[i]);
}

// ---------------------------------------------------------------------------
// Kernel A: h = neigh[262144,512] @ W1 ; pooled[b,:] = relu(max_n h + bias)
// BM=64 x BN=256 tile, 4 waves (2x2 of 32x128), BK=64, 16x16x32 bf16 MFMA.
// A staged as RAW F32 via global_load_lds (16-chunk swizzle ch^(r&15)),
// converted to bf16 at fragment-read time. B staged bf16 via global_load_lds
// (8-chunk swizzle g^(r&7)). A 64-row M-tile == 2 batch-groups of 32
// neighbors -> pool completes in-block (relu/max commute: pool raw h, then
// bias+relu once).
// ---------------------------------------------------------------------------
__global__ void __launch_bounds__(256) mlp_pool_kernel(
    const float* __restrict__ neigh,          // [B*32, 512] f32
    const unsigned short* __restrict__ w1t,   // [512,512] bf16, [n][k]
    const float* __restrict__ bias,           // [512] f32
    unsigned short* __restrict__ pooled)      // [B, 512] bf16
{
    __shared__ __align__(16) float As[64 * 64];   // 16 KB, [r][16 chunks swz]
    __shared__ __align__(16) short Bs[256 * 64];  // 32 KB, [r][8 chunks swz]
    __shared__ float pool_s[2][256];

    const int tid  = threadIdx.x;
    const int wave = tid >> 6;
    const int lane = tid & 63;
    const int quad = lane >> 4;
    const int l15  = lane & 15;
    const int mw = (wave >> 1) * 32;    // wave covers rows mw..mw+31
    const int nw = (wave & 1) * 128;    // and cols nw..nw+127

    const int m0 = (blockIdx.x >> 1) * 64;    // row tile in [B*32]
    const int n0 = (blockIdx.x & 1) * 256;    // col tile in D_HID

    // ---- staging address precompute (k-invariant) ----
    // A: ci = wave*256 + rr*64 + lane; r = ci>>4, pos = ci&15, ch = pos^(r&15)
    const float* agp[4];
#pragma unroll
    for (int rr = 0; rr < 4; ++rr) {
        int ci = wave * 256 + rr * 64 + lane;
        int r = ci >> 4, pos = ci & 15, ch = pos ^ (r & 15);
        agp[rr] = neigh + (size_t)(m0 + r) * D + ch * 4;
    }
    char* alp0 = (char*)As + wave * 4096 + lane * 16;
    // B: ci = wave*512 + rr*64 + lane; r = wave*64 + rr*8 + (lane>>3);
    //    g = (lane&7) ^ ((lane>>3)&7)  (rr-invariant since rr*8 % 8 == 0)
    const unsigned short* bgp0 = w1t +
        (size_t)(n0 + wave * 64 + (lane >> 3)) * D +
        ((lane & 7) ^ ((lane >> 3) & 7)) * 8;
    char* blp0 = (char*)Bs + wave * 8192 + lane * 16;

    floatx4 acc[2][8];
#pragma unroll
    for (int i = 0; i < 2; ++i)
#pragma unroll
        for (int j = 0; j < 8; ++j) acc[i][j] = (floatx4){0.f, 0.f, 0.f, 0.f};

    for (int kk = 0; kk < 8; ++kk) {
        const int k0 = kk * 64;
        __syncthreads();
#pragma unroll
        for (int rr = 0; rr < 4; ++rr)
            ld_lds16(agp[rr] + k0, alp0 + rr * 1024);
#pragma unroll
        for (int rr = 0; rr < 8; ++rr)
            ld_lds16(bgp0 + rr * 4096 + k0, blp0 + rr * 1024);
        __syncthreads();   // compiler drains vmcnt(0) before s_barrier

#pragma unroll
        for (int s = 0; s < 2; ++s) {
            short8_t af[2], bf[8];
#pragma unroll
            for (int mt = 0; mt < 2; ++mt) {
                int r = mw + mt * 16 + l15;          // r&15 == l15
                int c2 = s * 8 + quad * 2;           // first of 2 f32 chunks
                floatx4 a0 = *(const floatx4*)(
                    (const char*)As + r * 256 + ((c2 ^ l15) * 16));
                floatx4 a1 = *(const floatx4*)(
                    (const char*)As + r * 256 + (((c2 + 1) ^ l15) * 16));
                short8_t v;
                v[0] = (short)f2bf(a0[0]); v[1] = (short)f2bf(a0[1]);
                v[2] = (short)f2bf(a0[2]); v[3] = (short)f2bf(a0[3]);
                v[4] = (short)f2bf(a1[0]); v[5] = (short)f2bf(a1[1]);
                v[6] = (short)f2bf(a1[2]); v[7] = (short)f2bf(a1[3]);
                af[mt] = v;
            }
#pragma unroll
            for (int nt = 0; nt < 8; ++nt) {
                int r = nw + nt * 16 + l15;          // r&7 == l15&7
                int c = (s * 4 + quad) ^ (l15 & 7);
                bf[nt] = *(const short8_t*)((const char*)Bs + r * 128 + c * 16);
            }
#pragma unroll
            for (int mt = 0; mt < 2; ++mt)
#pragma unroll
                for (int nt = 0; nt < 8; ++nt)
                    acc[mt][nt] = __builtin_amdgcn_mfma_f32_16x16x32_bf16(
                        af[mt], bf[nt], acc[mt][nt], 0, 0, 0);
        }
    }

    // ---- max-pool raw h over the wave's 32-row batch group ----
    // C/D layout: row = quad*4 + rg (within 16-tile), col = l15.
#pragma unroll
    for (int nt = 0; nt < 8; ++nt) {
        float v = -3.4e38f;
#pragma unroll
        for (int mt = 0; mt < 2; ++mt)
#pragma unroll
            for (int rg = 0; rg < 4; ++rg) v = fmaxf(v, acc[mt][nt][rg]);
        v = fmaxf(v, __shfl_xor(v, 16));   // fold quad bit 0
        v = fmaxf(v, __shfl_xor(v, 32));   // fold quad bit 1
        if (lane < 16) pool_s[wave >> 1][nw + nt * 16 + l15] = v;
    }
    __syncthreads();
#pragma unroll
    for (int it = 0; it < 2; ++it) {
        int i = it * 256 + tid;
        int g = i >> 8, col = i & 255;
        float v = fmaxf(pool_s[g][col] + bias[n0 + col], 0.0f);
        pooled[(size_t)((m0 >> 5) + g) * D + n0 + col] = f2bf(v);
    }
}

// ---------------------------------------------------------------------------
// Kernel B: out = relu(pooled @ W2 + self @ W3), M=8192, N=512, K=512 (x2)
// Virtual K-loop of 16 blocks: kk<8 -> pooled/W2t (bf16), kk>=8 -> self/W3t.
// (unchanged from round 1 — not the measured bottleneck)
// ---------------------------------------------------------------------------
__global__ void __launch_bounds__(256) out_gemm_kernel(
    const unsigned short* __restrict__ pooled, // [B,512] bf16
    const float* __restrict__ selfv,           // [B,512] f32
    const unsigned short* __restrict__ w2t,    // neigh_w^T bf16 [n][k]
    const unsigned short* __restrict__ w3t,    // self_w^T bf16 [n][k]
    float* __restrict__ out)                   // [B,512] f32
{
    __shared__ __align__(16) short As[128 * 64];
    __shared__ __align__(16) short Bs[128 * 64];

    const int tid  = threadIdx.x;
    const int wave = tid >> 6;
    const int lane = tid & 63;
    const int quad = lane >> 4;
    const int l15  = lane & 15;
    const int mw = (wave >> 1) * 64;
    const int nw = (wave & 1) * 64;

    const int m0 = (blockIdx.x >> 2) * 128;
    const int n0 = (blockIdx.x & 3) * 128;

    floatx4 acc[4][4];
#pragma unroll
    for (int i = 0; i < 4; ++i)
#pragma unroll
        for (int j = 0; j < 4; ++j) acc[i][j] = (floatx4){0.f, 0.f, 0.f, 0.f};

    for (int kk = 0; kk < 16; ++kk) {
        const int k0 = (kk & 7) * 64;
        __syncthreads();
        if (kk < 8) {
#pragma unroll
            for (int rnd = 0; rnd < 4; ++rnd) {
                int l = rnd * 256 + tid;
                int r = l >> 3, g = l & 7;
                short8_t v = *reinterpret_cast<const short8_t*>(
                    pooled + (size_t)(m0 + r) * D + k0 + g * 8);
                *reinterpret_cast<short8_t*>(&As[r * 64 + ((g ^ (r & 7)) * 8)]) = v;
            }
#pragma unroll
            for (int rnd = 0; rnd < 4; ++rnd) {
                int l = rnd * 256 + tid;
                int r = l >> 3, g = l & 7;
                short8_t v = *reinterpret_cast<const short8_t*>(
                    w2t + (size_t)(n0 + r) * D + k0 + g * 8);
                *reinterpret_cast<short8_t*>(&Bs[r * 64 + ((g ^ (r & 7)) * 8)]) = v;
            }
        } else {
#pragma unroll
            for (int rnd = 0; rnd < 4; ++rnd) {
                int l = rnd * 256 + tid;
                int r = l >> 3, g = l & 7;
                const float4* src = reinterpret_cast<const float4*>(
                    selfv + (size_t)(m0 + r) * D + k0 + g * 8);
                float4 f0 = src[0];
                float4 f1 = src[1];
                short8_t v;
                v[0] = (short)f2bf(f0.x); v[1] = (short)f2bf(f0.y);
                v[2] = (short)f2bf(f0.z); v[3] = (short)f2bf(f0.w);
                v[4] = (short)f2bf(f1.x); v[5] = (short)f2bf(f1.y);
                v[6] = (short)f2bf(f1.z); v[7] = (short)f2bf(f1.w);
                *reinterpret_cast<short8_t*>(&As[r * 64 + ((g ^ (r & 7)) * 8)]) = v;
            }
#pragma unroll
            for (int rnd = 0; rnd < 4; ++rnd) {
                int l = rnd * 256 + tid;
                int r = l >> 3, g = l & 7;
                short8_t v = *reinterpret_cast<const short8_t*>(
                    w3t + (size_t)(n0 + r) * D + k0 + g * 8);
                *reinterpret_cast<short8_t*>(&Bs[r * 64 + ((g ^ (r & 7)) * 8)]) = v;
            }
        }
        __syncthreads();
#pragma unroll
        for (int s = 0; s < 2; ++s) {
            short8_t af[4], bfr[4];
#pragma unroll
            for (int mt = 0; mt < 4; ++mt) {
                int r = mw + mt * 16 + l15;
                int c = (s * 4 + quad) ^ (r & 7);
                af[mt] = *reinterpret_cast<const short8_t*>(&As[r * 64 + c * 8]);
            }
#pragma unroll
            for (int nt = 0; nt < 4; ++nt) {
                int r = nw + nt * 16 + l15;
                int c = (s * 4 + quad) ^ (r & 7);
                bfr[nt] = *reinterpret_cast<const short8_t*>(&Bs[r * 64 + c * 8]);
            }
#pragma unroll
            for (int mt = 0; mt < 4; ++mt)
#pragma unroll
                for (int nt = 0; nt < 4; ++nt)
                    acc[mt][nt] = __builtin_amdgcn_mfma_f32_16x16x32_bf16(
                        af[mt], bfr[nt], acc[mt][nt], 0, 0, 0);
        }
    }

#pragma unroll
    for (int mt = 0; mt < 4; ++mt)
#pragma unroll
        for (int nt = 0; nt < 4; ++nt)
#pragma unroll
            for (int rg = 0; rg < 4; ++rg) {
                int row = m0 + mw + mt * 16 + quad * 4 + rg;
                int col = n0 + nw + nt * 16 + l15;
                out[(size_t)row * D + col] = fmaxf(acc[mt][nt][rg], 0.0f);
            }
}

// ---------------------------------------------------------------------------
extern "C" void kernel_launch(void* const* d_in, const int* in_sizes, int n_in,
                              void* d_out, int out_size, void* d_ws, size_t ws_size,
                              hipStream_t stream) {
    const float* selfv = (const float*)d_in[0];   // [8192,512]
    const float* neigh = (const float*)d_in[1];   // [8192,32,512]
    const float* w1    = (const float*)d_in[2];   // mlp_w [512,512]
    const float* b1    = (const float*)d_in[3];   // mlp_b [512]
    const float* w2    = (const float*)d_in[4];   // neigh_w [512,512]
    const float* w3    = (const float*)d_in[5];   // self_w [512,512]
    float* out = (float*)d_out;

    // ws layout: pooled bf16 [8192*512] (8 MB) | w1t | w2t | w3t (512 KB each)
    unsigned short* pooled = (unsigned short*)d_ws;
    unsigned short* w1t = (unsigned short*)((char*)d_ws + 8388608);
    unsigned short* w2t = w1t + 262144;
    unsigned short* w3t = w2t + 262144;

    prep_weights<<<3072, 256, 0, stream>>>(w1, w2, w3, w1t, w2t, w3t);
    // M-tiles = 262144/64 = 4096, N-tiles = 2  -> 8192 blocks
    mlp_pool_kernel<<<8192, 256, 0, stream>>>(neigh, w1t, b1, pooled);
    // M-tiles = 8192/128 = 64, N-tiles = 4
    out_gemm_kernel<<<256, 256, 0, stream>>>(pooled, selfv, w2t, w3t, out);
}